// Round 1
// baseline (1342.686 us; speedup 1.0000x reference)
//
#include <hip/hip_runtime.h>

// VNMaxPool: B=4, N=1024, K=32, C=128, D=4 (1 type-0 row + 3 type-1 rows).
// dot[bn,k,c] = x0[k,c]*(x0[k,:]@W0 + b0)[c] + sum_j x1[k,j,c]*(x1[k,j,:]@W1)[c]
// idx[bn,c] = argmax_k dot ; gather x rows at idx -> (y0 [BN,1,C], y1 [BN,3,C]).
//
// Numerics: must match numpy argmax decisions. Projection = sequential fp32 FMA
// chain over c' (single accumulator, BLAS microkernel order). Final dot uses
// __fmul_rn/__fadd_rn so hipcc's default -ffp-contract=fast cannot fuse them
// (np computes x*d rounded, then a sequential size-4 sum).

#define CH 128
#define KS 32

__global__ __launch_bounds__(256, 2) void vnmaxpool_kernel(
    const float* __restrict__ x0, const float* __restrict__ x1,
    const float* __restrict__ W0, const float* __restrict__ b0,
    const float* __restrict__ W1, float* __restrict__ out, int BN)
{
  const int bn  = blockIdx.x;
  const int tid = threadIdx.x;
  const int c   = tid & (CH - 1);
  // k-group (0 or 1): uniform per wave; readfirstlane forces SGPR so the x-row
  // addresses below are provably uniform -> s_load_dwordx4 on the scalar pipe.
  const int kg = __builtin_amdgcn_readfirstlane(tid >> 7);
  const int k0 = kg * 16;

  const float* __restrict__ x0b = x0 + (size_t)bn * KS * CH;        // [32][128]
  const float* __restrict__ x1b = x1 + (size_t)bn * KS * 3 * CH;    // [32][3][128]

  // Projection accumulators: 16 k's x 4 rows (d=0 via W0, d=1..3 via W1).
  float acc0[16];
  float acc1[16][3];
#pragma unroll
  for (int i = 0; i < 16; ++i) {
    acc0[i] = 0.f; acc1[i][0] = 0.f; acc1[i][1] = 0.f; acc1[i][2] = 0.f;
  }

  // c' reduction in chunks of 4. W element (per-lane c) reused across 16 k's.
  for (int cc = 0; cc < CH; cc += 4) {
    float w0[4], w1[4];
#pragma unroll
    for (int i = 0; i < 4; ++i) {
      w0[i] = W0[(cc + i) * CH + c];   // coalesced, L2-hot
      w1[i] = W1[(cc + i) * CH + c];
    }
#pragma unroll
    for (int kk = 0; kk < 16; ++kk) {
      const int k = k0 + kk;
      const float4 a  = *(const float4*)(x0b + (size_t)k * CH + cc);           // uniform -> s_load
      const float4 v0 = *(const float4*)(x1b + (size_t)(k * 3 + 0) * CH + cc);
      const float4 v1 = *(const float4*)(x1b + (size_t)(k * 3 + 1) * CH + cc);
      const float4 v2 = *(const float4*)(x1b + (size_t)(k * 3 + 2) * CH + cc);
      // sequential FMA chain per accumulator: matches BLAS accumulation order
      acc0[kk] = fmaf(a.x, w0[0], acc0[kk]);
      acc0[kk] = fmaf(a.y, w0[1], acc0[kk]);
      acc0[kk] = fmaf(a.z, w0[2], acc0[kk]);
      acc0[kk] = fmaf(a.w, w0[3], acc0[kk]);
      acc1[kk][0] = fmaf(v0.x, w1[0], acc1[kk][0]);
      acc1[kk][0] = fmaf(v0.y, w1[1], acc1[kk][0]);
      acc1[kk][0] = fmaf(v0.z, w1[2], acc1[kk][0]);
      acc1[kk][0] = fmaf(v0.w, w1[3], acc1[kk][0]);
      acc1[kk][1] = fmaf(v1.x, w1[0], acc1[kk][1]);
      acc1[kk][1] = fmaf(v1.y, w1[1], acc1[kk][1]);
      acc1[kk][1] = fmaf(v1.z, w1[2], acc1[kk][1]);
      acc1[kk][1] = fmaf(v1.w, w1[3], acc1[kk][1]);
      acc1[kk][2] = fmaf(v2.x, w1[0], acc1[kk][2]);
      acc1[kk][2] = fmaf(v2.y, w1[1], acc1[kk][2]);
      acc1[kk][2] = fmaf(v2.z, w1[2], acc1[kk][2]);
      acc1[kk][2] = fmaf(v2.w, w1[3], acc1[kk][2]);
    }
  }

  // Per-thread dot + argmax over this thread's 16 k's (strict > = first max).
  const float b0c = b0[c];
  float bm = -__builtin_inff();
  int   bk = 0;
#pragma unroll
  for (int kk = 0; kk < 16; ++kk) {
    const int k = k0 + kk;
    const float xc0   = x0b[(size_t)k * CH + c];                 // per-lane, coalesced, L2-hot
    const float xc1_0 = x1b[(size_t)(k * 3 + 0) * CH + c];
    const float xc1_1 = x1b[(size_t)(k * 3 + 1) * CH + c];
    const float xc1_2 = x1b[(size_t)(k * 3 + 2) * CH + c];
    const float d0v = __fadd_rn(acc0[kk], b0c);                  // matmul then +b0, np order
    float s = __fmul_rn(xc0, d0v);                               // rounded mul (no contract)
    s = __fadd_rn(s, __fmul_rn(xc1_0, acc1[kk][0]));
    s = __fadd_rn(s, __fmul_rn(xc1_1, acc1[kk][1]));
    s = __fadd_rn(s, __fmul_rn(xc1_2, acc1[kk][2]));
    if (s > bm) { bm = s; bk = kk; }
  }

  __shared__ float rm[256];
  __shared__ int   rk[256];
  rm[tid] = bm;
  rk[tid] = k0 + bk;
  __syncthreads();

  if (tid < CH) {
    const float m0 = rm[tid];
    const float m1 = rm[CH + tid];
    const int kstar = (m1 > m0) ? rk[CH + tid] : rk[tid];        // tie -> lower k group

    const float y0  = x0b[(size_t)kstar * CH + tid];
    const float y10 = x1b[(size_t)(kstar * 3 + 0) * CH + tid];
    const float y11 = x1b[(size_t)(kstar * 3 + 1) * CH + tid];
    const float y12 = x1b[(size_t)(kstar * 3 + 2) * CH + tid];

    out[(size_t)bn * CH + tid] = y0;                             // y0: [BN,1,C]
    float* __restrict__ out1 = out + (size_t)BN * CH;            // y1: [BN,3,C]
    out1[((size_t)bn * 3 + 0) * CH + tid] = y10;
    out1[((size_t)bn * 3 + 1) * CH + tid] = y11;
    out1[((size_t)bn * 3 + 2) * CH + tid] = y12;
  }
}

extern "C" void kernel_launch(void* const* d_in, const int* in_sizes, int n_in,
                              void* d_out, int out_size, void* d_ws, size_t ws_size,
                              hipStream_t stream) {
  const float* x0 = (const float*)d_in[0];
  const float* x1 = (const float*)d_in[1];
  const float* W0 = (const float*)d_in[2];
  const float* b0 = (const float*)d_in[3];
  const float* W1 = (const float*)d_in[4];
  float* out = (float*)d_out;
  const int BN = in_sizes[0] / (KS * CH);   // 4096
  vnmaxpool_kernel<<<BN, 256, 0, stream>>>(x0, x1, W0, b0, W1, out, BN);
}

// Round 4
// 457.731 us; speedup vs baseline: 2.9334x; 2.9334x over previous
//
#include <hip/hip_runtime.h>

// VNMaxPool: B=4, N=1024, K=32, C=128, D=4 (1 type-0 row + 3 type-1 rows).
// Per bn: proj[k,d,c] = x[k,d,:] @ (d==0 ? W0 : W1), d0 gets +b0.
// dot[k,c] = sum_d x[k,d,c]*proj[k,d,c]; argmax over k per c; gather x rows.
//
// Numerics: per-output accumulation is a single sequential fmaf chain over c'
// ascending (chunks of 4) — bitwise-identical to the round-1 passing kernel.
// Final dot uses __fmul_rn/__fadd_rn (no fp-contract) in d-ascending order.
// Argmax = first-max (strict >, ascending k everywhere).
//
// Round-1 lesson: bulk x traffic through the scalar pipe (s_load) serialized
// the kernel at 355 GB/s. Now x is staged once into LDS (vector path), read
// back as wave-broadcast ds_read_b128; W streams per-lane from L1/L2.
// (Rounds 2-3 died in harness infra — ExceptionGroup / "container failed
// twice", no kernel diagnostic; kernel audited clean. Third submit.)

#define CH 128
#define KS 32

typedef float f4 __attribute__((ext_vector_type(4)));

__global__ __launch_bounds__(256, 2) void vnmaxpool_kernel(
    const float* __restrict__ x0, const float* __restrict__ x1,
    const float* __restrict__ W0, const float* __restrict__ b0,
    const float* __restrict__ W1, float* __restrict__ out, int BN)
{
  const int tid = threadIdx.x;
  const int bn  = blockIdx.x;
  if (bn >= BN) return;

  __shared__ float xl[16384];        // 64 KB: [0..4095]=x0 (32k x 128), [4096..]=x1 (32k x 3 x 128)
  __shared__ float rm[8][CH];        // per-(row-group, channel) max
  __shared__ int   rk[8][CH];        // per-(row-group, channel) arg-k

  const float* __restrict__ gx0 = x0 + (size_t)bn * (KS * CH);       // 4096 floats
  const float* __restrict__ gx1 = x1 + (size_t)bn * (KS * 3 * CH);   // 12288 floats

  // ---- stage x into LDS (natural row-major), coalesced f4 + contiguous ds_write_b128 ----
#pragma unroll
  for (int t = 0; t < 16; ++t) {
    const int f4i = t * 256 + tid;                 // float4 index 0..4095 (uniform branch per t)
    f4 v;
    if (f4i < 1024) v = *(const f4*)(gx0 + (size_t)f4i * 4);
    else            v = *(const f4*)(gx1 + (size_t)(f4i - 1024) * 4);
    *(f4*)(&xl[(size_t)f4i * 4]) = v;
  }
  __syncthreads();

  const float* __restrict__ xl0 = xl;              // [k][c']
  const float* __restrict__ xl1 = xl + 4096;       // [k][j][c']

  const int tc = tid & 31;                         // channel quad: c = tc*4 + cq
  const int tr = tid >> 5;                         // k quad: k = tr*4 + kk

  // accumulators: acc[kk*4+d][cq] = proj[k=tr*4+kk][d][c=tc*4+cq]
  float acc[16][4];
#pragma unroll
  for (int r = 0; r < 16; ++r)
#pragma unroll
    for (int cq = 0; cq < 4; ++cq) acc[r][cq] = 0.f;

  const float* __restrict__ Wp0 = W0 + tc * 4;
  const float* __restrict__ Wp1 = W1 + tc * 4;

  // one chunk = 4 consecutive c' values; W fragments double-buffered (A/B)
  f4 wa0[4], wa1[4], wb0[4], wb1[4];
#pragma unroll
  for (int i = 0; i < 4; ++i) {                    // prologue: chunk 0 -> A
    wa0[i] = *(const f4*)(Wp0 + (size_t)i * CH);
    wa1[i] = *(const f4*)(Wp1 + (size_t)i * CH);
  }

  // FMA body for one chunk (cc4 = chunk index, w0f/w1f = W fragments)
#define CHUNK(cc4, w0f, w1f)                                                   \
  {                                                                            \
    f4 xf0[4], xf1[4][3];                                                      \
    _Pragma("unroll")                                                          \
    for (int kk = 0; kk < 4; ++kk) {                                           \
      const int k = tr * 4 + kk;                                               \
      xf0[kk]    = *(const f4*)(xl0 + (size_t)k * CH + (cc4) * 4);             \
      xf1[kk][0] = *(const f4*)(xl1 + (size_t)(k * 3 + 0) * CH + (cc4) * 4);   \
      xf1[kk][1] = *(const f4*)(xl1 + (size_t)(k * 3 + 1) * CH + (cc4) * 4);   \
      xf1[kk][2] = *(const f4*)(xl1 + (size_t)(k * 3 + 2) * CH + (cc4) * 4);   \
    }                                                                          \
    _Pragma("unroll")                                                          \
    for (int i = 0; i < 4; ++i) {            /* c' ascending within chunk */   \
      _Pragma("unroll")                                                        \
      for (int kk = 0; kk < 4; ++kk) {                                         \
        _Pragma("unroll")                                                      \
        for (int cq = 0; cq < 4; ++cq) {                                       \
          acc[kk*4+0][cq] = fmaf(xf0[kk][i],    (w0f)[i][cq], acc[kk*4+0][cq]);\
          acc[kk*4+1][cq] = fmaf(xf1[kk][0][i], (w1f)[i][cq], acc[kk*4+1][cq]);\
          acc[kk*4+2][cq] = fmaf(xf1[kk][1][i], (w1f)[i][cq], acc[kk*4+2][cq]);\
          acc[kk*4+3][cq] = fmaf(xf1[kk][2][i], (w1f)[i][cq], acc[kk*4+3][cq]);\
        }                                                                      \
      }                                                                        \
    }                                                                          \
  }

  for (int cc4 = 0; cc4 < 32; cc4 += 2) {
    { // prefetch chunk cc4+1 -> B (cc4+1 <= 31, always valid)
      const int nb = cc4 + 1;
#pragma unroll
      for (int i = 0; i < 4; ++i) {
        wb0[i] = *(const f4*)(Wp0 + (size_t)(nb * 4 + i) * CH);
        wb1[i] = *(const f4*)(Wp1 + (size_t)(nb * 4 + i) * CH);
      }
    }
    CHUNK(cc4, wa0, wa1);
    { // prefetch chunk cc4+2 -> A (wrap harmlessly at the end)
      const int na = (cc4 + 2) & 31;
#pragma unroll
      for (int i = 0; i < 4; ++i) {
        wa0[i] = *(const f4*)(Wp0 + (size_t)(na * 4 + i) * CH);
        wa1[i] = *(const f4*)(Wp1 + (size_t)(na * 4 + i) * CH);
      }
    }
    CHUNK(cc4 + 1, wb0, wb1);
  }
#undef CHUNK

  // ---- per-thread dot + argmax over this thread's 4 k's ----
  const f4 b0v = *(const f4*)(b0 + tc * 4);
  float bm[4];
  int   bk[4];
#pragma unroll
  for (int cq = 0; cq < 4; ++cq) { bm[cq] = -__builtin_inff(); bk[cq] = 0; }

#pragma unroll
  for (int kk = 0; kk < 4; ++kk) {
    const int k = tr * 4 + kk;
    const f4 X0  = *(const f4*)(xl0 + (size_t)k * CH + tc * 4);
    const f4 X10 = *(const f4*)(xl1 + (size_t)(k * 3 + 0) * CH + tc * 4);
    const f4 X11 = *(const f4*)(xl1 + (size_t)(k * 3 + 1) * CH + tc * 4);
    const f4 X12 = *(const f4*)(xl1 + (size_t)(k * 3 + 2) * CH + tc * 4);
#pragma unroll
    for (int cq = 0; cq < 4; ++cq) {
      const float d0v = __fadd_rn(acc[kk*4+0][cq], b0v[cq]);   // matmul then +b0
      float s = __fmul_rn(X0[cq], d0v);                        // rounded mul, no contract
      s = __fadd_rn(s, __fmul_rn(X10[cq], acc[kk*4+1][cq]));
      s = __fadd_rn(s, __fmul_rn(X11[cq], acc[kk*4+2][cq]));
      s = __fadd_rn(s, __fmul_rn(X12[cq], acc[kk*4+3][cq]));
      if (s > bm[cq]) { bm[cq] = s; bk[cq] = k; }              // strict > = first max
    }
  }

#pragma unroll
  for (int cq = 0; cq < 4; ++cq) {
    rm[tr][tc * 4 + cq] = bm[cq];
    rk[tr][tc * 4 + cq] = bk[cq];
  }
  __syncthreads();

  // ---- merge 8 row-groups (ascending k; strict > keeps lowest k) + gather ----
  if (tid < CH) {
    const int c = tid;
    float best = rm[0][c];
    int   kb   = rk[0][c];
#pragma unroll
    for (int g = 1; g < 8; ++g) {
      if (rm[g][c] > best) { best = rm[g][c]; kb = rk[g][c]; }
    }
    out[(size_t)bn * CH + c] = xl0[(size_t)kb * CH + c];       // y0: [BN,1,C]
    float* __restrict__ out1 = out + (size_t)BN * CH;          // y1: [BN,3,C]
    out1[((size_t)bn * 3 + 0) * CH + c] = xl1[(size_t)(kb * 3 + 0) * CH + c];
    out1[((size_t)bn * 3 + 1) * CH + c] = xl1[(size_t)(kb * 3 + 1) * CH + c];
    out1[((size_t)bn * 3 + 2) * CH + c] = xl1[(size_t)(kb * 3 + 2) * CH + c];
  }
}

extern "C" void kernel_launch(void* const* d_in, const int* in_sizes, int n_in,
                              void* d_out, int out_size, void* d_ws, size_t ws_size,
                              hipStream_t stream) {
  const float* x0 = (const float*)d_in[0];
  const float* x1 = (const float*)d_in[1];
  const float* W0 = (const float*)d_in[2];
  const float* b0 = (const float*)d_in[3];
  const float* W1 = (const float*)d_in[4];
  float* out = (float*)d_out;
  const int BN = in_sizes[0] / (KS * CH);   // 4096
  vnmaxpool_kernel<<<BN, 256, 0, stream>>>(x0, x1, W0, b0, W1, out, BN);
}